// Round 1
// baseline (249.142 us; speedup 1.0000x reference)
//
#include <hip/hip_runtime.h>
#include <hip/hip_bf16.h>
#include <cstdint>
#include <cstddef>

#define SEQ_N 2048
#define DIM   1024
#define NHEAD 16
#define DH    64

typedef __bf16 bf16;
typedef __attribute__((ext_vector_type(8))) __bf16 bf16x8;
typedef __attribute__((ext_vector_type(4))) __bf16 bf16x4;
typedef __attribute__((ext_vector_type(4))) float f32x4;

// async global->LDS 16B copy: LDS dest = wave-uniform base + lane*16
__device__ __forceinline__ void gl_lds16(const bf16* g, bf16* l) {
    __builtin_amdgcn_global_load_lds(
        (const __attribute__((address_space(1))) unsigned int*)g,
        (__attribute__((address_space(3))) unsigned int*)l, 16, 0, 0);
}

// ---------------------------------------------------------------------------
// prep: fused input cast (x, pos -> bf16) + all weight transposes.
// blocks [0,6144): cast 1024 elems each (4M x + 2M pos).
// blocks [6144,10304): 32x32 transpose tiles (Wq|Wkv -> WqkvT, Wo, Wp).
// ---------------------------------------------------------------------------
__global__ __launch_bounds__(256) void prep_kernel(
    const float* __restrict__ x, const float* __restrict__ pos,
    const float* __restrict__ Wq, const float* __restrict__ Wkv,
    const float* __restrict__ Wo, const float* __restrict__ Wp,
    bf16* __restrict__ xb, bf16* __restrict__ posb,
    bf16* __restrict__ WqkvT, bf16* __restrict__ WoT, bf16* __restrict__ WpT)
{
    int bid = blockIdx.x;
    if (bid < 6144) {
        const int NX = 4096 * 1024;
        int i = (bid * 256 + threadIdx.x) * 4;
        if (i < NX) {
            float4 v = *(const float4*)&x[i];
            xb[i + 0] = (bf16)v.x; xb[i + 1] = (bf16)v.y;
            xb[i + 2] = (bf16)v.z; xb[i + 3] = (bf16)v.w;
        } else {
            int j = i - NX;
            float4 v = *(const float4*)&pos[j];
            posb[j + 0] = (bf16)v.x; posb[j + 1] = (bf16)v.y;
            posb[j + 2] = (bf16)v.z; posb[j + 3] = (bf16)v.w;
        }
        return;
    }
    __shared__ float t[32][33];
    bid -= 6144;
    const float* src; bf16* dst; int tidx, nx, N;
    if (bid < 1024)      { src = Wq;  dst = WqkvT;                       tidx = bid;        nx = 32; N = 1024; }
    else if (bid < 3072) { src = Wkv; dst = WqkvT + (size_t)1024 * 1024; tidx = bid - 1024; nx = 64; N = 2048; }
    else if (bid < 4096) { src = Wo;  dst = WoT;                         tidx = bid - 3072; nx = 32; N = 1024; }
    else                 { src = Wp;  dst = WpT;                         tidx = bid - 4096; nx = 2;  N = 64;   }
    int n0 = (tidx % nx) * 32, k0 = (tidx / nx) * 32;
    int tx = threadIdx.x & 31, ty = threadIdx.x >> 5;
    #pragma unroll
    for (int r = ty; r < 32; r += 8)
        t[r][tx] = src[(size_t)(k0 + r) * N + n0 + tx];
    __syncthreads();
    #pragma unroll
    for (int r = ty; r < 32; r += 8)
        dst[(size_t)(n0 + r) * 1024 + k0 + tx] = (bf16)t[tx][r];
}

// ---------------------------------------------------------------------------
// qkv projection + p projection, one dispatch. grid (25, 32).
// bx in [0,24): 128x128 tile of [q|k|v] = xb @ WqkvT^T + bias.
//   bx<16 -> q/k natural layout; bx>=16 -> V transposed (b,h,d,t) via an
//   LDS bounce so global stores are 16B vectors over contiguous t.
// bx==24 (by<16): p = posb @ WpT^T + bp in fragment-ready layout.
// ---------------------------------------------------------------------------
__global__ __launch_bounds__(256) void qkvp_kernel(
    const bf16* __restrict__ xb, const bf16* __restrict__ WqkvT,
    const bf16* __restrict__ posb, const bf16* __restrict__ WpT,
    const float* __restrict__ bq, const float* __restrict__ bkv,
    const float* __restrict__ bp,
    bf16* __restrict__ qbuf, bf16* __restrict__ kbuf,
    bf16* __restrict__ vtbuf, bf16* __restrict__ pfrag)
{
    __shared__ __align__(16) bf16 sm[128 * 132];   // At|Bt staging / V bounce
    bf16* At = sm;
    bf16* Bt = sm + 128 * 64;
    const int tid = threadIdx.x, w = tid >> 6, lane = tid & 63;
    const int q = lane >> 4, ln15 = lane & 15;
    const int lr = lane >> 3, c_log = (lane & 7) ^ lr;
    const int bx = blockIdx.x, by = blockIdx.y;
    const int m0 = by * 128;

    if (bx == 24) {
        if (by >= 16) return;
        f32x4 acc[2][4] = {};
        for (int k0 = 0; k0 < 1024; k0 += 64) {
            __syncthreads();
            #pragma unroll
            for (int t = 0; t < 4; ++t)
                gl_lds16(&posb[(size_t)(m0 + 32 * w + 8 * t + lr) * 1024 + k0 + c_log * 8],
                         &At[(32 * w + 8 * t) * 64]);
            #pragma unroll
            for (int t = 0; t < 2; ++t)
                gl_lds16(&WpT[(size_t)(16 * w + 8 * t + lr) * 1024 + k0 + c_log * 8],
                         &Bt[(16 * w + 8 * t) * 64]);
            __syncthreads();
            bf16x8 bfr[2][4];
            #pragma unroll
            for (int ks = 0; ks < 2; ++ks)
                #pragma unroll
                for (int sn = 0; sn < 4; ++sn) {
                    int rb = 16 * sn + ln15;
                    bfr[ks][sn] = *(const bf16x8*)&Bt[(rb * 8 + ((4 * ks + q) ^ (rb & 7))) * 8];
                }
            #pragma unroll
            for (int sm2 = 0; sm2 < 2; ++sm2) {
                int ra = 32 * w + 16 * sm2 + ln15;
                #pragma unroll
                for (int ks = 0; ks < 2; ++ks) {
                    bf16x8 af = *(const bf16x8*)&At[(ra * 8 + ((4 * ks + q) ^ (ra & 7))) * 8];
                    #pragma unroll
                    for (int sn = 0; sn < 4; ++sn)
                        acc[sm2][sn] = __builtin_amdgcn_mfma_f32_16x16x32_bf16(
                            af, bfr[ks][sn], acc[sm2][sn], 0, 0, 0);
                }
            }
        }
        #pragma unroll
        for (int sm2 = 0; sm2 < 2; ++sm2)
            #pragma unroll
            for (int sn = 0; sn < 4; ++sn)
                #pragma unroll
                for (int r = 0; r < 4; ++r) {
                    int row = m0 + 32 * w + 16 * sm2 + 4 * q + r;
                    int d = 16 * sn + ln15;
                    int sb = row >> 4, lnp = row & 15;
                    int ks2 = d >> 5, qd = (d >> 3) & 3, e = d & 7;
                    pfrag[(((size_t)sb * 2 + ks2) * 64 + qd * 16 + lnp) * 8 + e] =
                        (bf16)(acc[sm2][sn][r] + bp[d]);
                }
        return;
    }

    // ---- qkv GEMM tile ----
    const int n0 = bx * 128;
    const int wm = w >> 1, wn = w & 1;
    f32x4 acc[4][4] = {};

    for (int k0 = 0; k0 < 1024; k0 += 64) {
        __syncthreads();
        #pragma unroll
        for (int t = 0; t < 4; ++t) {
            int r = 32 * w + 8 * t + lr;
            gl_lds16(&xb[(size_t)(m0 + r) * 1024 + k0 + c_log * 8],
                     &At[(32 * w + 8 * t) * 64]);
            gl_lds16(&WqkvT[(size_t)(n0 + r) * 1024 + k0 + c_log * 8],
                     &Bt[(32 * w + 8 * t) * 64]);
        }
        __syncthreads();

        bf16x8 af[2][4], bfr[2][4];
        #pragma unroll
        for (int ks = 0; ks < 2; ++ks)
            #pragma unroll
            for (int s = 0; s < 4; ++s) {
                int ra = 64 * wm + 16 * s + ln15;
                af[ks][s]  = *(const bf16x8*)&At[(ra * 8 + ((4 * ks + q) ^ (ra & 7))) * 8];
                int rb = 64 * wn + 16 * s + ln15;
                bfr[ks][s] = *(const bf16x8*)&Bt[(rb * 8 + ((4 * ks + q) ^ (rb & 7))) * 8];
            }
        #pragma unroll
        for (int ks = 0; ks < 2; ++ks)
            #pragma unroll
            for (int si = 0; si < 4; ++si)
                #pragma unroll
                for (int sj = 0; sj < 4; ++sj)
                    acc[si][sj] = __builtin_amdgcn_mfma_f32_16x16x32_bf16(
                        af[ks][si], bfr[ks][sj], acc[si][sj], 0, 0, 0);
    }

    if (bx < 16) {
        // q / k natural layout
        #pragma unroll
        for (int si = 0; si < 4; ++si)
            #pragma unroll
            for (int sj = 0; sj < 4; ++sj)
                #pragma unroll
                for (int r = 0; r < 4; ++r) {
                    int row = m0 + 64 * wm + 16 * si + 4 * q + r;
                    int col = n0 + 64 * wn + 16 * sj + ln15;
                    float v = acc[si][sj][r] + (col < 1024 ? bq[col] : bkv[col - 1024]);
                    if (col < 1024) qbuf[(size_t)row * 1024 + col] = (bf16)v;
                    else            kbuf[(size_t)row * 1024 + (col - 1024)] = (bf16)v;
                }
    } else {
        // V: transpose to (b,h,d,t) via LDS bounce, 16B coalesced stores
        __syncthreads();   // all waves done reading At/Bt
        #pragma unroll
        for (int si = 0; si < 4; ++si)
            #pragma unroll
            for (int sj = 0; sj < 4; ++sj) {
                int dL = 64 * wn + 16 * sj + ln15;        // 0..127
                int tL = 64 * wm + 16 * si + 4 * q;       // +r
                float bias = bkv[1024 + (bx - 16) * 128 + dL];
                bf16x4 o4;
                #pragma unroll
                for (int r = 0; r < 4; ++r)
                    o4[r] = (bf16)(acc[si][sj][r] + bias);
                *(bf16x4*)&sm[dL * 132 + tL] = o4;
            }
        __syncthreads();
        const int b = m0 >> 11;
        const int t0 = m0 & 2047;
        const int h0 = (bx - 16) * 2;
        #pragma unroll
        for (int p = 0; p < 16; ++p) {
            int d = (tid >> 5) + 8 * p;
            int t = (tid & 31) * 4;
            bf16x4 v4 = *(const bf16x4*)&sm[d * 132 + t];
            int rowv = (b * NHEAD + h0 + (d >> 6)) * DH + (d & 63);
            *(bf16x4*)&vtbuf[(size_t)rowv * SEQ_N + t0 + t] = v4;
        }
    }
}

// ---------------------------------------------------------------------------
// MFMA flash attention, transposed scores S^T = K.Q^T (stats at lane=i),
// O^T = V^T.P^T, register S2 ring + tiny LDS bias table.
//
// Block remap (XCD-aware, L2-local): flat id f = bx + 32*by.
//   xcd  = f & 7          -> under linear round-robin, this block's XCD
//   slot = f >> 3
//   bh   = 4*xcd + (slot & 3)   -> each XCD hosts only 4 (b,h) pairs:
//                                  K+V working set 2 MB + pfrag 0.5 MB < 4 MB L2
//   g    = (slot >> 2) & 7, pass = slot >> 5
//   qblk = {g, 15-g, 16+g, 31-g}[pass]  (bijective over 0..31 per bh)
// Under CU = (f/8)%32 (same assumption as the previous balance trick), each
// CU's 4 resident blocks share ONE bh (L1/L2 reuse of the same K/V) and
// their iteration counts sum to (g+1)+(16-g)+(17+g)+(32-g) = 66 -> balanced.
// ---------------------------------------------------------------------------
__global__ __launch_bounds__(256, 4) void attn_mfma_kernel(
    const bf16* __restrict__ qb,    // [4096][1024]
    const bf16* __restrict__ kb,    // [4096][1024]
    const bf16* __restrict__ vt,    // [(b,h,d)][2048]
    const bf16* __restrict__ pfrag, // fragment-ready p
    bf16* __restrict__ ob)          // [4096][1024]
{
    const int f    = (int)blockIdx.x + ((int)blockIdx.y << 5);
    const int slot = f >> 3;
    const int bh   = ((f & 7) << 2) + (slot & 3);
    const int bi   = bh >> 4, hh = bh & 15;
    const int g    = (slot >> 2) & 7;
    const int pass = slot >> 5;
    const int qblk = (pass == 0) ? g
                   : (pass == 1) ? 15 - g
                   : (pass == 2) ? 16 + g
                   :               31 - g;
    const int i0 = qblk << 6;
    const int tid = threadIdx.x, w = tid >> 6, lane = tid & 63;
    const int q = lane >> 4, ln15 = lane & 15;
    const int lr = lane >> 3, c_log = (lane & 7) ^ lr;

    __shared__ __align__(16) bf16 smem[17664];
    bf16* Qs  = smem;                    // 64x64 staging (reused as S2L)
    bf16* S2L = smem + w * 1344;         // per-wave 16 x 84
    bf16* Ks  = smem + 5376;
    bf16* Vs  = smem + 9472;
    bf16* Pw  = smem + 13568 + w * 1024;

    const bf16* qbase = qb + ((size_t)(bi * SEQ_N + i0)) * DIM + hh * DH;
    const bf16* kbase = kb + ((size_t)bi * SEQ_N) * DIM + hh * DH;
    const bf16* vbase = vt + ((size_t)(bi * NHEAD + hh) * DH) * SEQ_N;

    #pragma unroll
    for (int t = 0; t < 2; ++t)
        gl_lds16(qbase + (size_t)(16 * w + 8 * t + lr) * DIM + c_log * 8,
                 &Qs[(16 * w + 8 * t) * 64]);
    __syncthreads();
    bf16x8 qf0, qf1;
    {
        int rq = 16 * w + ln15;
        qf0 = *(const bf16x8*)&Qs[(rq * 8 + ((q    ) ^ (rq & 7))) * 8];
        qf1 = *(const bf16x8*)&Qs[(rq * 8 + ((4 + q) ^ (rq & 7))) * 8];
    }
    __syncthreads();   // q-frags extracted; S2L region now writable

    const int A0 = 127 - 4 * qblk - w;
    f32x4 s2r4;
    {
        bf16x8 f0 = *(const bf16x8*)&pfrag[(((size_t)A0 * 2 + 0) * 64 + lane) * 8];
        bf16x8 f1 = *(const bf16x8*)&pfrag[(((size_t)A0 * 2 + 1) * 64 + lane) * 8];
        f32x4 a = {0.f, 0.f, 0.f, 0.f};
        a = __builtin_amdgcn_mfma_f32_16x16x32_bf16(f0, qf0, a, 0, 0, 0);
        a = __builtin_amdgcn_mfma_f32_16x16x32_bf16(f1, qf1, a, 0, 0, 0);
        s2r4 = a;
    }

    float m_run = -1e30f, l_run = 0.f;
    f32x4 O_T[4] = {};

    for (int jt = 0; jt <= qblk; ++jt) {
        const int j0 = jt << 6;

        bf16x8 pfA[4][2];
        #pragma unroll
        for (int s = 1; s <= 4; ++s) {
            int sb = A0 + 4 * jt + s;
            if (sb > 127) sb = 127;
            pfA[s-1][0] = *(const bf16x8*)&pfrag[(((size_t)sb * 2 + 0) * 64 + lane) * 8];
            pfA[s-1][1] = *(const bf16x8*)&pfrag[(((size_t)sb * 2 + 1) * 64 + lane) * 8];
        }
        #pragma unroll
        for (int t = 0; t < 2; ++t) {
            int r = 16 * w + 8 * t + lr;
            gl_lds16(kbase + (size_t)(j0 + r) * DIM + c_log * 8,
                     &Ks[(16 * w + 8 * t) * 64]);
            gl_lds16(vbase + (size_t)r * SEQ_N + j0 + c_log * 8,
                     &Vs[(16 * w + 8 * t) * 64]);
        }

        f32x4 s2r[5];
        s2r[0] = s2r4;
        #pragma unroll
        for (int s = 1; s <= 4; ++s) {
            f32x4 a = {0.f, 0.f, 0.f, 0.f};
            a = __builtin_amdgcn_mfma_f32_16x16x32_bf16(pfA[s-1][0], qf0, a, 0, 0, 0);
            a = __builtin_amdgcn_mfma_f32_16x16x32_bf16(pfA[s-1][1], qf1, a, 0, 0, 0);
            s2r[s] = a;
        }
        s2r4 = s2r[4];
        #pragma unroll
        for (int s = 0; s < 5; ++s)
            #pragma unroll
            for (int r = 0; r < 4; ++r)
                S2L[ln15 * 84 + 16 * s + 4 * q + r] = (bf16)s2r[s][r];

        __syncthreads();

        float sv[4][4];
        #pragma unroll
        for (int sn = 0; sn < 4; ++sn) {
            int rk = 16 * sn + ln15;
            bf16x8 k0f = *(const bf16x8*)&Ks[(rk * 8 + ((q    ) ^ (rk & 7))) * 8];
            bf16x8 k1f = *(const bf16x8*)&Ks[(rk * 8 + ((4 + q) ^ (rk & 7))) * 8];
            f32x4 a = {0.f, 0.f, 0.f, 0.f};
            a = __builtin_amdgcn_mfma_f32_16x16x32_bf16(k0f, qf0, a, 0, 0, 0);
            a = __builtin_amdgcn_mfma_f32_16x16x32_bf16(k1f, qf1, a, 0, 0, 0);
            #pragma unroll
            for (int r = 0; r < 4; ++r) {
                int jl = 16 * sn + 4 * q + r;
                float b = (float)S2L[ln15 * 84 + 15 - ln15 + jl];
                sv[sn][r] = (a[r] + b) * 0.125f;
            }
        }
        if (jt == qblk) {
            #pragma unroll
            for (int sn = 0; sn < 4; ++sn)
                #pragma unroll
                for (int r = 0; r < 4; ++r)
                    if (16 * sn + 4 * q + r > 16 * w + ln15)
                        sv[sn][r] = -1e30f;
        }

        float mx = sv[0][0];
        #pragma unroll
        for (int sn = 0; sn < 4; ++sn)
            #pragma unroll
            for (int r = 0; r < 4; ++r)
                mx = fmaxf(mx, sv[sn][r]);
        mx = fmaxf(mx, __shfl_xor(mx, 16));
        mx = fmaxf(mx, __shfl_xor(mx, 32));
        const float mn = fmaxf(m_run, mx);
        float sum = 0.f;
        #pragma unroll
        for (int sn = 0; sn < 4; ++sn)
            #pragma unroll
            for (int r = 0; r < 4; ++r) {
                float e = __expf(sv[sn][r] - mn);
                sv[sn][r] = e;
                sum += e;
            }
        sum += __shfl_xor(sum, 16);
        sum += __shfl_xor(sum, 32);
        const float alpha = __expf(m_run - mn);
        l_run = l_run * alpha + sum;
        m_run = mn;

        #pragma unroll
        for (int sn = 0; sn < 4; ++sn)
            #pragma unroll
            for (int r = 0; r < 4; ++r) {
                int chunk = (2 * sn + (q >> 1)) ^ (ln15 & 7);
                Pw[ln15 * 64 + chunk * 8 + 4 * (q & 1) + r] = (bf16)sv[sn][r];
            }
        #pragma unroll
        for (int sd = 0; sd < 4; ++sd)
            #pragma unroll
            for (int r = 0; r < 4; ++r)
                O_T[sd][r] *= alpha;

        __builtin_amdgcn_s_waitcnt(0);

        #pragma unroll
        for (int ks = 0; ks < 2; ++ks) {
            bf16x8 pT = *(const bf16x8*)&Pw[ln15 * 64 + (((4 * ks + q) ^ (ln15 & 7))) * 8];
            #pragma unroll
            for (int sd = 0; sd < 4; ++sd) {
                int rv = 16 * sd + ln15;
                bf16x8 vf = *(const bf16x8*)&Vs[(rv * 8 + ((4 * ks + q) ^ (rv & 7))) * 8];
                O_T[sd] = __builtin_amdgcn_mfma_f32_16x16x32_bf16(vf, pT, O_T[sd], 0, 0, 0);
            }
        }
        __syncthreads();
    }

    const float inv = 1.0f / l_run;
    const size_t row = (size_t)bi * SEQ_N + i0 + 16 * w + ln15;
    #pragma unroll
    for (int sd = 0; sd < 4; ++sd) {
        bf16x4 o4;
        #pragma unroll
        for (int r = 0; r < 4; ++r)
            o4[r] = (bf16)(O_T[sd][r] * inv);
        *(bf16x4*)&ob[row * DIM + hh * DH + 16 * sd + 4 * q] = o4;
    }
}

// ---------------------------------------------------------------------------
// out = abuf @ WoT^T + bo, fp32 out. 128x64 tiles -> grid (16,32), 2/CU.
// ---------------------------------------------------------------------------
__global__ __launch_bounds__(256) void outproj_kernel(
    const bf16* __restrict__ ab, const bf16* __restrict__ WoT,
    const float* __restrict__ bo, float* __restrict__ out)
{
    __shared__ __align__(16) bf16 At[128 * 64];
    __shared__ __align__(16) bf16 Bt[64 * 64];
    const int tid = threadIdx.x, w = tid >> 6, lane = tid & 63;
    const int q = lane >> 4, ln15 = lane & 15;
    const int lr = lane >> 3, c_log = (lane & 7) ^ lr;
    const int m0 = blockIdx.y * 128, n0 = blockIdx.x * 64;

    f32x4 acc[2][4] = {};
    for (int k0 = 0; k0 < 1024; k0 += 64) {
        __syncthreads();
        #pragma unroll
        for (int t = 0; t < 4; ++t)
            gl_lds16(&ab[(size_t)(m0 + 32 * w + 8 * t + lr) * 1024 + k0 + c_log * 8],
                     &At[(32 * w + 8 * t) * 64]);
        #pragma unroll
        for (int t = 0; t < 2; ++t)
            gl_lds16(&WoT[(size_t)(n0 + 16 * w + 8 * t + lr) * 1024 + k0 + c_log * 8],
                     &Bt[(16 * w + 8 * t) * 64]);
        __syncthreads();

        bf16x8 bfr[2][4];
        #pragma unroll
        for (int ks = 0; ks < 2; ++ks)
            #pragma unroll
            for (int sn = 0; sn < 4; ++sn) {
                int rb = 16 * sn + ln15;
                bfr[ks][sn] = *(const bf16x8*)&Bt[(rb * 8 + ((4 * ks + q) ^ (rb & 7))) * 8];
            }
        #pragma unroll
        for (int sm2 = 0; sm2 < 2; ++sm2) {
            int ra = 32 * w + 16 * sm2 + ln15;
            #pragma unroll
            for (int ks = 0; ks < 2; ++ks) {
                bf16x8 af = *(const bf16x8*)&At[(ra * 8 + ((4 * ks + q) ^ (ra & 7))) * 8];
                #pragma unroll
                for (int sn = 0; sn < 4; ++sn)
                    acc[sm2][sn] = __builtin_amdgcn_mfma_f32_16x16x32_bf16(
                        af, bfr[ks][sn], acc[sm2][sn], 0, 0, 0);
            }
        }
    }
    #pragma unroll
    for (int sm2 = 0; sm2 < 2; ++sm2)
        #pragma unroll
        for (int sn = 0; sn < 4; ++sn) {
            int col = n0 + 16 * sn + ln15;
            float bias = bo[col];
            #pragma unroll
            for (int r = 0; r < 4; ++r) {
                int row = m0 + 32 * w + 16 * sm2 + 4 * q + r;
                out[(size_t)row * 1024 + col] = acc[sm2][sn][r] + bias;
            }
        }
}

// ---------------------------------------------------------------------------
extern "C" void kernel_launch(void* const* d_in, const int* in_sizes, int n_in,
                              void* d_out, int out_size, void* d_ws, size_t ws_size,
                              hipStream_t stream)
{
    const float* x    = (const float*)d_in[0];
    const float* pos  = (const float*)d_in[1];
    const float* Wq   = (const float*)d_in[2];
    const float* bq   = (const float*)d_in[3];
    const float* Wkv  = (const float*)d_in[4];
    const float* bkv  = (const float*)d_in[5];
    const float* Wp   = (const float*)d_in[6];
    const float* bp   = (const float*)d_in[7];
    const float* Wo   = (const float*)d_in[8];
    const float* bo   = (const float*)d_in[9];
    float* out = (float*)d_out;

    const int M = 2 * SEQ_N;   // 4096
    char* ws = (char*)d_ws;
    bf16* xb     = (bf16*)ws;  ws += (size_t)M * DIM * 2;
    bf16* posb   = (bf16*)ws;  ws += (size_t)SEQ_N * DIM * 2;
    bf16* WqkvT  = (bf16*)ws;  ws += (size_t)3072 * 1024 * 2;
    bf16* WoT    = (bf16*)ws;  ws += (size_t)DIM * DIM * 2;
    bf16* WpT    = (bf16*)ws;  ws += (size_t)DH * DIM * 2;
    bf16* qbuf   = (bf16*)ws;  ws += (size_t)M * DIM * 2;
    bf16* kbuf   = (bf16*)ws;  ws += (size_t)M * DIM * 2;
    bf16* vtbuf  = (bf16*)ws;  ws += (size_t)M * DIM * 2;
    bf16* pfrag  = (bf16*)ws;  ws += (size_t)512 * 1024;
    bf16* abuf   = (bf16*)ws;

    dim3 blk(256);
    prep_kernel<<<dim3(10304), blk, 0, stream>>>(
        x, pos, Wq, Wkv, Wo, Wp, xb, posb, WqkvT, WoT, WpT);

    qkvp_kernel<<<dim3(25, 32), blk, 0, stream>>>(
        xb, WqkvT, posb, WpT, bq, bkv, bp, qbuf, kbuf, vtbuf, pfrag);

    attn_mfma_kernel<<<dim3(32, 32), blk, 0, stream>>>(
        qbuf, kbuf, vtbuf, pfrag, abuf);

    outproj_kernel<<<dim3(16, 32), blk, 0, stream>>>(
        abuf, WoT, bo, out);
}